// Round 9
// baseline (349.664 us; speedup 1.0000x reference)
//
#include <hip/hip_runtime.h>
#include <math.h>

#define NT 100000
#define NP 50000
#define NE 800000
#define H 128
#define NB 196
#define BCAP 8192

#define CDIV(a,b) (((a)+(b)-1)/(b))

typedef __attribute__((ext_vector_type(8))) short s16x8;
typedef __attribute__((ext_vector_type(4))) short s16x4;
typedef __attribute__((ext_vector_type(4))) unsigned short u16x4;
typedef __attribute__((ext_vector_type(4))) float f32x4;

static __device__ __forceinline__ float dot4(float4 a, float4 b){
  return a.x*b.x + a.y*b.y + a.z*b.z + a.w*b.w;
}
static __device__ __forceinline__ float b2f(unsigned short u){
  union { unsigned int i; float f; } c; c.i = ((unsigned int)u) << 16; return c.f;
}
static __device__ __forceinline__ unsigned short f2b(float f){
  union { float f; unsigned int i; } c; c.f = f;
  unsigned int x = c.i;
  unsigned int r = (x + 0x7fffu + ((x >> 16) & 1u)) >> 16;   // RNE
  return (unsigned short)r;
}
static __device__ __forceinline__ float4 cvt4(ushort4 h){
  return make_float4(b2f(h.x), b2f(h.y), b2f(h.z), b2f(h.w));
}
static __device__ __forceinline__ float4 cvt4u(u16x4 h){
  return make_float4(b2f(h[0]), b2f(h[1]), b2f(h[2]), b2f(h[3]));
}

// ---------- rank-1 helper vectors ----------
__global__ void kvec4(const float* __restrict__ e, const float* __restrict__ be,
    const float* W0, const float* bi0, float* u0, float* w0,
    const float* W1, const float* bi1, float* u1, float* w1,
    const float* W2, const float* bi2, float* u2, float* w2,
    const float* W3, const float* bi3, float* u3, float* w3){
  const float *W, *bi; float *u, *w;
  switch (blockIdx.x){
    case 0: W=W0; bi=bi0; u=u0; w=w0; break;
    case 1: W=W1; bi=bi1; u=u1; w=w1; break;
    case 2: W=W2; bi=bi2; u=u2; w=w2; break;
    default:W=W3; bi=bi3; u=u3; w=w3; break;
  }
  int j = threadIdx.x;
  float su = 0.f, sw = 0.f;
  for (int i = 0; i < H; ++i) {
    float wv = W[i*H + j];
    su += e[i]*wv;
    sw += be[i]*wv;
  }
  u[j] = su;
  w[j] = sw + bi[j];
}

// ---------- setup: Wqk = Wq @ Wk^T, bqk = bq @ Wk^T ----------
__global__ void ksetup(const float* __restrict__ Wq, const float* __restrict__ Wk,
                       const float* __restrict__ bq, float* __restrict__ Wqk,
                       float* __restrict__ bqk){
  int i = blockIdx.x;     // t1-input dim
  int m = threadIdx.x;    // qk output dim (p1 dim)
  __shared__ float wqr[H];
  wqr[m] = Wq[i*H + m];
  __syncthreads();
  const float* wkr = Wk + m*H;   // Wk[m][j]
  float s = 0.f;
  for (int j = 0; j < H; ++j) s += wqr[j] * wkr[j];
  Wqk[i*H + m] = s;
  if (i == 0){
    float t = 0.f;
    for (int j = 0; j < H; ++j) t += bq[j] * wkr[j];
    bqk[m] = t;
  }
}
// vqb = Wq @ bk, c0 = bq . bk
__global__ void kvqb(const float* __restrict__ Wq, const float* __restrict__ bq,
                     const float* __restrict__ bk, float* __restrict__ vqb,
                     float* __restrict__ c0){
  int i = threadIdx.x;
  float s = 0.f;
  for (int j = 0; j < H; ++j) s += Wq[i*H + j]*bk[j];
  vqb[i] = s;
  if (i == 0){
    float t = 0.f;
    for (int j = 0; j < H; ++j) t += bq[j]*bk[j];
    *c0 = t;
  }
}

// ---------- MFMA GEMM pieces ----------
static __device__ __forceinline__ void stage_w(const float* __restrict__ W,
    unsigned short* __restrict__ WH, unsigned short* __restrict__ WL, int tid){
  #pragma unroll
  for (int it = 0; it < 16; ++it){
    int gid = it*256 + tid;
    int n  = gid & 127;
    int kg = gid >> 7;
    int k0 = kg*4;
    float w0 = W[(k0+0)*H + n];
    float w1 = W[(k0+1)*H + n];
    float w2 = W[(k0+2)*H + n];
    float w3 = W[(k0+3)*H + n];
    unsigned short h0=f2b(w0), h1=f2b(w1), h2=f2b(w2), h3=f2b(w3);
    s16x4 hv; hv[0]=(short)h0; hv[1]=(short)h1; hv[2]=(short)h2; hv[3]=(short)h3;
    s16x4 lv; lv[0]=(short)f2b(w0-b2f(h0)); lv[1]=(short)f2b(w1-b2f(h1));
              lv[2]=(short)f2b(w2-b2f(h2)); lv[3]=(short)f2b(w3-b2f(h3));
    int base = n*128 + (((kg>>1) ^ (n&15))<<3) + ((kg&1)<<2);
    *(s16x4*)(WH + base) = hv;
    *(s16x4*)(WL + base) = lv;
  }
}

template<bool USE_AL>
static __device__ __forceinline__ void mfma_pass(const s16x8 AH[2][4], const s16x8 AL[2][4],
    const unsigned short* __restrict__ WH, const unsigned short* __restrict__ WL,
    int l15, int l4, f32x4 acc[2][8]){
  #pragma unroll
  for (int g = 0; g < 2; ++g)
    #pragma unroll
    for (int t = 0; t < 8; ++t){ acc[g][t][0]=0.f; acc[g][t][1]=0.f; acc[g][t][2]=0.f; acc[g][t][3]=0.f; }
  #pragma unroll
  for (int s = 0; s < 4; ++s){
    #pragma unroll
    for (int t = 0; t < 8; ++t){
      int n = t*16 + l15;
      int off = n*128 + (((s*4 + l4) ^ l15)<<3);
      s16x8 BH = *(const s16x8*)(WH + off);
      s16x8 BL = *(const s16x8*)(WL + off);
      #pragma unroll
      for (int g = 0; g < 2; ++g){
        acc[g][t] = __builtin_amdgcn_mfma_f32_16x16x32_bf16(AH[g][s], BH, acc[g][t], 0,0,0);
        acc[g][t] = __builtin_amdgcn_mfma_f32_16x16x32_bf16(AH[g][s], BL, acc[g][t], 0,0,0);
        if constexpr (USE_AL)
          acc[g][t] = __builtin_amdgcn_mfma_f32_16x16x32_bf16(AL[g][s], BH, acc[g][t], 0,0,0);
      }
    }
  }
}

#define EPI_WRITE(ACC, BIAS)                                                    \
  {                                                                             \
    float bb[8];                                                                \
    _Pragma("unroll")                                                           \
    for (int t = 0; t < 8; ++t) bb[t] = BIAS[t*16 + l15];                       \
    _Pragma("unroll")                                                           \
    for (int g = 0; g < 2; ++g){                                                \
      _Pragma("unroll")                                                         \
      for (int t = 0; t < 8; ++t){                                              \
        _Pragma("unroll")                                                       \
        for (int r = 0; r < 4; ++r)                                             \
          EPI[w*32 + g*16 + l4*4 + r][t*16 + l15] = ACC[g][t][r] + bb[t];       \
      }                                                                         \
    }                                                                           \
  }

template<int BF>
static __device__ __forceinline__ void epi_store(void* Y, int ld, int of, int row0, int M,
                                                 int tid, const float (*EPI)[132]){
  #pragma unroll
  for (int it = 0; it < 16; ++it){
    int fid = it*256 + tid;
    int r = fid >> 5, c4 = (fid & 31) << 2;
    int grow = row0 + r;
    if (grow < M){
      float4 v = *(const float4*)&EPI[r][c4];
      if constexpr (BF){
        ushort4 hv; hv.x=f2b(v.x); hv.y=f2b(v.y); hv.z=f2b(v.z); hv.w=f2b(v.w);
        *(ushort4*)((unsigned short*)Y + (size_t)grow*ld + of + c4) = hv;
      } else {
        *(float4*)((float*)Y + (size_t)grow*ld + of + c4) = v;
      }
    }
  }
}

static __device__ __forceinline__ void dots_epi(const f32x4 (&acc)[2][8],
    const float* __restrict__ bias, const float* __restrict__ uvec,
    const float* __restrict__ wvec, float2* __restrict__ acout,
    int row0, int M, int w, int l15, int l4){
  float ub[8], wb[8], bb[8];
  #pragma unroll
  for (int t=0;t<8;++t){ ub[t]=uvec[t*16+l15]; wb[t]=wvec[t*16+l15]; bb[t]=bias[t*16+l15]; }
  #pragma unroll
  for (int g=0; g<2; ++g){
    #pragma unroll
    for (int r=0;r<4;++r){
      float pa=0.f, pc=0.f;
      #pragma unroll
      for (int t=0;t<8;++t){ float y=acc[g][t][r]+bb[t]; pa+=y*ub[t]; pc+=y*wb[t]; }
      #pragma unroll
      for (int o=1;o<16;o<<=1){ pa+=__shfl_xor(pa,o); pc+=__shfl_xor(pc,o); }
      int row=row0+w*32+g*16+l4*4+r;
      if (l15==0 && row<M) acout[row]=make_float2(pa,pc);
    }
  }
}

static __device__ __forceinline__ void load_a_f32(const float* __restrict__ X, int M,
    int row0, int w, int l15, int l4, s16x8 AH[2][4], s16x8 AL[2][4]){
  #pragma unroll
  for (int g = 0; g < 2; ++g){
    int row = row0 + w*32 + g*16 + l15;
    const float* xr = X + (size_t)row*H;
    bool ok = row < M;
    #pragma unroll
    for (int s = 0; s < 4; ++s){
      int kb = s*32 + l4*8;
      float4 f0 = ok ? *(const float4*)(xr+kb)   : make_float4(0.f,0.f,0.f,0.f);
      float4 f1 = ok ? *(const float4*)(xr+kb+4) : make_float4(0.f,0.f,0.f,0.f);
      float xs[8] = {f0.x,f0.y,f0.z,f0.w,f1.x,f1.y,f1.z,f1.w};
      s16x8 h, lo;
      #pragma unroll
      for (int e = 0; e < 8; ++e){
        unsigned short hh = f2b(xs[e]);
        h[e]  = (short)hh;
        lo[e] = (short)f2b(xs[e] - b2f(hh));
      }
      AH[g][s] = h; AL[g][s] = lo;
    }
  }
}
static __device__ __forceinline__ void load_a_bf16(const unsigned short* __restrict__ Xb, int M,
    int row0, int w, int l15, int l4, s16x8 AH[2][4]){
  #pragma unroll
  for (int g = 0; g < 2; ++g){
    int row = row0 + w*32 + g*16 + l15;
    const unsigned short* xr = Xb + (size_t)row*H;
    bool ok = row < M;
    #pragma unroll
    for (int s = 0; s < 4; ++s){
      s16x8 h = {0,0,0,0,0,0,0,0};
      if (ok) h = *(const s16x8*)(xr + s*32 + l4*8);
      AH[g][s] = h;
    }
  }
}

// ---------- fused phrase-side GEMM: 4 passes sharing X fragments ----------
__launch_bounds__(256)
__global__ void mgemm_ph(const float* __restrict__ X, int M,
    const float* __restrict__ Wq, const float* __restrict__ bq,
    const float* __restrict__ uk, const float* __restrict__ wk, float2* __restrict__ ac1,
    const float* __restrict__ Ws, const float* __restrict__ bs, unsigned short* __restrict__ S1b,
    const float* __restrict__ Wk, const float* __restrict__ bk,
    const float* __restrict__ uq, const float* __restrict__ wq, float2* __restrict__ ac2,
    const float* __restrict__ Wv, const float* __restrict__ bv, unsigned short* __restrict__ Vb){
  __shared__ __align__(16) char smem[128*132*4];
  unsigned short* WH = (unsigned short*)smem;
  unsigned short* WL = WH + 16384;
  float (*EPI)[132] = (float(*)[132])smem;
  int tid=threadIdx.x, lane=tid&63, w=tid>>6, l15=lane&15, l4=lane>>4;
  int row0 = blockIdx.x*128;

  s16x8 AH[2][4], AL[2][4];
  load_a_f32(X, M, row0, w, l15, l4, AH, AL);

  f32x4 acc[2][8];
  stage_w(Wq, WH, WL, tid); __syncthreads();
  mfma_pass<true>(AH, AL, WH, WL, l15, l4, acc);
  dots_epi(acc, bq, uk, wk, ac1, row0, M, w, l15, l4);
  __syncthreads();
  stage_w(Ws, WH, WL, tid); __syncthreads();
  mfma_pass<true>(AH, AL, WH, WL, l15, l4, acc);
  __syncthreads(); EPI_WRITE(acc, bs); __syncthreads();
  epi_store<1>(S1b, H, 0, row0, M, tid, EPI);
  __syncthreads();
  stage_w(Wk, WH, WL, tid); __syncthreads();
  mfma_pass<true>(AH, AL, WH, WL, l15, l4, acc);
  dots_epi(acc, bk, uq, wq, ac2, row0, M, w, l15, l4);
  __syncthreads();
  stage_w(Wv, WH, WL, tid); __syncthreads();
  mfma_pass<true>(AH, AL, WH, WL, l15, l4, acc);
  __syncthreads(); EPI_WRITE(acc, bv); __syncthreads();
  epi_store<1>(Vb, H, 0, row0, M, tid, EPI);
}

// ---------- tconv3 front GEMM: qk = t1@Wqk + bqk (fp32), qb dots, s3 -> Sb ----------
__launch_bounds__(256)
__global__ void mgemm_t3(const unsigned short* __restrict__ T1b, int M,
    const float* __restrict__ Wqk, const float* __restrict__ bqk,
    float* __restrict__ qkf,
    const float* __restrict__ vqb, const float* __restrict__ c0,
    float* __restrict__ qbf,
    const float* __restrict__ Ws, const float* __restrict__ bs,
    unsigned short* __restrict__ Sb){
  __shared__ __align__(16) char smem[128*132*4];
  unsigned short* WH = (unsigned short*)smem;
  unsigned short* WL = WH + 16384;
  float (*EPI)[132] = (float(*)[132])smem;
  int tid=threadIdx.x, lane=tid&63, w=tid>>6, l15=lane&15, l4=lane>>4;
  int row0 = blockIdx.x*128;

  s16x8 AH[2][4];
  load_a_bf16(T1b, M, row0, w, l15, l4, AH);

  // qb[row] = t1 . vqb + c0
  float cc0 = *c0;
  #pragma unroll
  for (int g = 0; g < 2; ++g){
    float p = 0.f;
    #pragma unroll
    for (int s = 0; s < 4; ++s){
      #pragma unroll
      for (int e = 0; e < 8; ++e)
        p += b2f((unsigned short)AH[g][s][e]) * vqb[s*32 + l4*8 + e];
    }
    p += __shfl_xor(p, 16);
    p += __shfl_xor(p, 32);
    int row = row0 + w*32 + g*16 + l15;
    if (l4 == 0 && row < M) qbf[row] = p + cc0;
  }

  stage_w(Wqk, WH, WL, tid); __syncthreads();
  f32x4 acc[2][8];
  mfma_pass<false>(AH, nullptr, WH, WL, l15, l4, acc);
  __syncthreads();
  EPI_WRITE(acc, bqk);
  __syncthreads();
  epi_store<0>(qkf, H, 0, row0, M, tid, EPI);
  __syncthreads();

  stage_w(Ws, WH, WL, tid); __syncthreads();
  f32x4 acc2[2][8];
  mfma_pass<false>(AH, nullptr, WH, WL, l15, l4, acc2);
  __syncthreads();
  EPI_WRITE(acc2, bs);
  __syncthreads();
  epi_store<1>(Sb, H, 0, row0, M, tid, EPI);
}

// ---------- tconv3 back GEMM: O = Opre@Wv + bv (deg-gated), beta-combine -> t2 ----------
__launch_bounds__(256)
__global__ void mgemm_cmb(const unsigned short* __restrict__ Opre, int M,
    const float* __restrict__ Wv, const float* __restrict__ bv,
    const unsigned short* __restrict__ Sb, const float* __restrict__ Wb,
    const int* __restrict__ deg,
    unsigned short* __restrict__ T2b){
  __shared__ __align__(16) unsigned short WH[16384];
  __shared__ __align__(16) unsigned short WL[16384];
  __shared__ __align__(16) unsigned short SLDS[128][128];
  int tid=threadIdx.x, lane=tid&63, w=tid>>6, l15=lane&15, l4=lane>>4;
  int row0 = blockIdx.x*128;

  s16x8 AH[2][4];
  load_a_bf16(Opre, M, row0, w, l15, l4, AH);

  stage_w(Wv, WH, WL, tid);
  #pragma unroll
  for (int it = 0; it < 8; ++it){
    int id = it*256 + tid;
    int r = id >> 4, c8 = (id & 15) << 3;
    int grow = row0 + r;
    s16x8 sv = {0,0,0,0,0,0,0,0};
    if (grow < M) sv = *(const s16x8*)(Sb + (size_t)grow*H + c8);
    *(s16x8*)&SLDS[r][c8] = sv;
  }
  __syncthreads();

  f32x4 acc[2][8];
  mfma_pass<false>(AH, nullptr, WH, WL, l15, l4, acc);

  float bvv[8], wbA[8], wbB[8], wbC[8];
  #pragma unroll
  for (int t = 0; t < 8; ++t){
    int col = t*16 + l15;
    bvv[t] = bv[col];
    wbA[t] = Wb[col]; wbB[t] = Wb[H + col]; wbC[t] = Wb[2*H + col];
  }
  #pragma unroll
  for (int g = 0; g < 2; ++g){
    #pragma unroll
    for (int r = 0; r < 4; ++r){
      int rl = w*32 + g*16 + l4*4 + r;
      int row = row0 + rl;
      // zero-degree nodes: reference out = 0 (empty segment) -> no bias
      float bsc = (row < M && deg[row] > 0) ? 1.f : 0.f;
      float o[8], sk[8];
      float part = 0.f;
      #pragma unroll
      for (int t = 0; t < 8; ++t){
        o[t] = acc[g][t][r] + bvv[t]*bsc;
        sk[t] = b2f(SLDS[rl][t*16 + l15]);
        part += o[t]*wbA[t] + sk[t]*wbB[t] + (o[t]-sk[t])*wbC[t];
      }
      #pragma unroll
      for (int of = 1; of < 16; of <<= 1) part += __shfl_xor(part, of);
      float beta = 1.f/(1.f + __expf(-part));
      if (row < M){
        unsigned short* dr = T2b + (size_t)row*H;
        #pragma unroll
        for (int t = 0; t < 8; ++t){
          float vv = beta*sk[t] + (1.f-beta)*o[t];
          dr[t*16 + l15] = f2b(vv);
        }
      }
    }
  }
}

// ---------- generic 1-pass GEMM (bf16 X) : head ----------
__launch_bounds__(256)
__global__ void mgemm_head(const unsigned short* __restrict__ Xb, int M,
    const float* __restrict__ W1, const float* __restrict__ b1,
    float* __restrict__ Y1){
  __shared__ __align__(16) char smem[128*132*4];
  unsigned short* WH = (unsigned short*)smem;
  unsigned short* WL = WH + 16384;
  float (*EPI)[132] = (float(*)[132])smem;
  int tid=threadIdx.x, lane=tid&63, w=tid>>6, l15=lane&15, l4=lane>>4;
  int row0 = blockIdx.x*128;

  s16x8 AH[2][4];
  load_a_bf16(Xb, M, row0, w, l15, l4, AH);

  stage_w(W1, WH, WL, tid); __syncthreads();
  f32x4 acc[2][8];
  mfma_pass<false>(AH, nullptr, WH, WL, l15, l4, acc);
  __syncthreads();
  EPI_WRITE(acc, b1);
  __syncthreads();
  epi_store<0>(Y1, H, 0, row0, M, tid, EPI);
}

// ---------- passA: bucket-bin edges ----------
template<int GATHER>
__launch_bounds__(256)
__global__ void passA(const int* __restrict__ dst, const int* __restrict__ src,
                      const float* __restrict__ xv, int shift,
                      int* __restrict__ bcnt, int2* __restrict__ out, int n){
  __shared__ int hist[NB];
  __shared__ int base[NB];
  __shared__ int cur[NB];
  int tid = threadIdx.x;
  for (int i = tid; i < NB; i += 256){ hist[i]=0; cur[i]=0; }
  __syncthreads();
  int e0 = blockIdx.x*2048;
  int d[8], s[8];
  #pragma unroll
  for (int k = 0; k < 8; ++k){
    int i = e0 + k*256 + tid;
    if (i < n){ d[k] = dst[i]; s[k] = src[i]; }
    else d[k] = -1;
  }
  #pragma unroll
  for (int k = 0; k < 8; ++k)
    if (d[k] >= 0) atomicAdd(&hist[d[k]>>shift], 1);
  __syncthreads();
  for (int b = tid; b < NB; b += 256)
    base[b] = hist[b] ? atomicAdd(&bcnt[b], hist[b]) : 0;
  __syncthreads();
  #pragma unroll
  for (int k = 0; k < 8; ++k){
    if (d[k] >= 0){
      int b = d[k] >> shift;
      int loc = atomicAdd(&cur[b], 1);
      int2 rec;
      if constexpr (GATHER) rec.x = __float_as_int(xv[s[k]]);
      else                  rec.x = s[k];
      rec.y = d[k] - (b << shift);
      out[(size_t)b*BCAP + base[b] + loc] = rec;
    }
  }
}

// ---------- passB phrase ----------
__launch_bounds__(512)
__global__ void passB_ph(const int* __restrict__ bcnt, const int2* __restrict__ sorted,
                         const float2* __restrict__ ac, float2* __restrict__ dsv, int np){
  __shared__ float2 acl[256];
  __shared__ float accx[256];
  __shared__ float accy[256];
  int b = blockIdx.x, tid = threadIdx.x;
  int p0 = b*256;
  if (tid < 256){
    int p = p0 + tid;
    acl[tid] = (p < np) ? ac[p] : make_float2(0.f,0.f);
    accx[tid] = 0.f; accy[tid] = 0.f;
  }
  __syncthreads();
  int n = bcnt[b];
  const int2* e = sorted + (size_t)b*BCAP;
  const float RS = 0.08838834764831845f;
  for (int i = tid; i < n; i += 512){
    int2 ed = e[i];
    float x = __int_as_float(ed.x);
    float2 a = acl[ed.y];
    float ex = __expf((x*a.x + a.y)*RS);
    atomicAdd(&accx[ed.y], ex);
    atomicAdd(&accy[ed.y], ex*x);
  }
  __syncthreads();
  if (tid < 256){
    int p = p0 + tid;
    if (p < np) dsv[p] = make_float2(accx[tid], accy[tid]);
  }
}

// ---------- passB token: per-bucket CSR ----------
__launch_bounds__(512)
__global__ void passB_tok(const int* __restrict__ bcnt, const int2* __restrict__ sorted,
                          int* __restrict__ rowptr, int* __restrict__ deg,
                          int* __restrict__ srcs, int ntok){
  __shared__ int cnt[512];
  __shared__ int scn[512];
  __shared__ int cur[512];
  int b = blockIdx.x, tid = threadIdx.x;
  cnt[tid] = 0; cur[tid] = 0;
  __syncthreads();
  int n = bcnt[b];
  const int2* e = sorted + (size_t)b*BCAP;
  for (int i = tid; i < n; i += 512) atomicAdd(&cnt[e[i].y], 1);
  __syncthreads();
  int myc = cnt[tid];
  scn[tid] = myc;
  __syncthreads();
  for (int off = 1; off < 512; off <<= 1){
    int u = (tid >= off) ? scn[tid-off] : 0;
    __syncthreads();
    scn[tid] += u;
    __syncthreads();
  }
  int excl = scn[tid] - myc;
  int tok = b*512 + tid;
  if (tok < ntok){ rowptr[tok] = b*BCAP + excl; deg[tok] = myc; }
  __syncthreads();
  cnt[tid] = excl;
  __syncthreads();
  for (int i = tid; i < n; i += 512){
    int2 ed = e[i];
    int pos = cnt[ed.y] + atomicAdd(&cur[ed.y], 1);
    srcs[(size_t)b*BCAP + pos] = ed.x;
  }
}

// ---------- beta gate + combine; OB: bf16 output ----------
template<int OB>
static __device__ __forceinline__ void beta_combine(float4 o, float4 sk,
    const float* __restrict__ Wb, int lane, bool leaky, void* __restrict__ dstRow){
  float4 wb0 = *(const float4*)&Wb[lane*4];
  float4 wb1 = *(const float4*)&Wb[H   + lane*4];
  float4 wb2 = *(const float4*)&Wb[2*H + lane*4];
  float4 dv = make_float4(o.x-sk.x, o.y-sk.y, o.z-sk.z, o.w-sk.w);
  float part = dot4(o,wb0) + dot4(sk,wb1) + dot4(dv,wb2);
  #pragma unroll
  for (int off=1; off<32; off<<=1) part += __shfl_xor(part, off);
  float beta = 1.f/(1.f + __expf(-part));
  float4 r;
  r.x = beta*sk.x + (1.f-beta)*o.x;
  r.y = beta*sk.y + (1.f-beta)*o.y;
  r.z = beta*sk.z + (1.f-beta)*o.z;
  r.w = beta*sk.w + (1.f-beta)*o.w;
  if (leaky){
    r.x = r.x>0.f? r.x : 0.01f*r.x;
    r.y = r.y>0.f? r.y : 0.01f*r.y;
    r.z = r.z>0.f? r.z : 0.01f*r.z;
    r.w = r.w>0.f? r.w : 0.01f*r.w;
  }
  if constexpr (OB){
    ushort4 h; h.x=f2b(r.x); h.y=f2b(r.y); h.z=f2b(r.z); h.w=f2b(r.w);
    *(ushort4*)((unsigned short*)dstRow + lane*4) = h;
  } else {
    *(float4*)((float*)dstRow + lane*4) = r;
  }
}

__global__ void kcomb1(const float2* __restrict__ dsv,
                       const float* __restrict__ uv, const float* __restrict__ wv,
                       const unsigned short* __restrict__ S, const float* __restrict__ Wb,
                       unsigned short* __restrict__ out, int n){
  int gid = (blockIdx.x*blockDim.x + threadIdx.x) >> 5;
  int lane = threadIdx.x & 31;
  if (gid >= n) return;
  float2 ds = dsv[gid];
  float d = ds.x, sv = ds.y;
  float inv = 1.f/(d + 1e-16f);
  float4 u4 = *(const float4*)&uv[lane*4];
  float4 w4 = *(const float4*)&wv[lane*4];
  float4 o = make_float4((sv*u4.x + d*w4.x)*inv, (sv*u4.y + d*w4.y)*inv,
                         (sv*u4.z + d*w4.z)*inv, (sv*u4.w + d*w4.w)*inv);
  u16x4 sh4 = __builtin_nontemporal_load((const u16x4*)(S + (size_t)gid*H + lane*4));
  float4 sk = cvt4u(sh4);
  beta_combine<1>(o, sk, Wb, lane, true, out + (size_t)gid*H);
}

// ---------- tconv2: no-max, 2-way unrolled bf16 V gather ----------
__global__ void knode2(const float* __restrict__ x_tok, const float2* __restrict__ ac,
                       const unsigned short* __restrict__ Vb,
                       const int* __restrict__ rowptr, const int* __restrict__ deg,
                       const int* __restrict__ srcs,
                       const float* __restrict__ us, const float* __restrict__ ws,
                       const float* __restrict__ Wb, unsigned short* __restrict__ out, int n){
  int gid = (blockIdx.x*blockDim.x + threadIdx.x) >> 5;
  int lane = threadIdx.x & 31;
  if (gid >= n) return;
  float xt = x_tok[gid];
  int rp = rowptr[gid], dg = deg[gid];
  const float RS = 0.08838834764831845f;
  float d = 0.f;
  float4 acc = make_float4(0.f,0.f,0.f,0.f);
  int i = 0;
  for (; i+2 <= dg; i += 2){
    int spA = srcs[rp+i], spB = srcs[rp+i+1];
    ushort4 hA = *(const ushort4*)(Vb + (size_t)spA*H + lane*4);
    ushort4 hB = *(const ushort4*)(Vb + (size_t)spB*H + lane*4);
    float2 aA = ac[spA], aB = ac[spB];
    float eA = __expf((xt*aA.x + aA.y)*RS);
    float eB = __expf((xt*aB.x + aB.y)*RS);
    float4 vA = cvt4(hA), vB = cvt4(hB);
    d += eA + eB;
    acc.x += eA*vA.x + eB*vB.x;
    acc.y += eA*vA.y + eB*vB.y;
    acc.z += eA*vA.z + eB*vB.z;
    acc.w += eA*vA.w + eB*vB.w;
  }
  if (i < dg){
    int sp = srcs[rp+i];
    ushort4 hv = *(const ushort4*)(Vb + (size_t)sp*H + lane*4);
    float2 a = ac[sp];
    float e = __expf((xt*a.x + a.y)*RS);
    float4 v = cvt4(hv);
    d += e;
    acc.x += e*v.x; acc.y += e*v.y; acc.z += e*v.z; acc.w += e*v.w;
  }
  float inv = 1.f/(d + 1e-16f);
  float4 o = make_float4(acc.x*inv, acc.y*inv, acc.z*inv, acc.w*inv);
  float4 u4 = *(const float4*)&us[lane*4];
  float4 w4 = *(const float4*)&ws[lane*4];
  float4 sk = make_float4(xt*u4.x+w4.x, xt*u4.y+w4.y, xt*u4.z+w4.z, xt*u4.w+w4.w);
  beta_combine<1>(o, sk, Wb, lane, true, out + (size_t)gid*H);
}

// ---------- tconv3 node: gather p1 only (256B/edge), fp32 qk ----------
__global__ void knode3n(const float* __restrict__ qkf, const float* __restrict__ qbf,
                        const unsigned short* __restrict__ P1b,
                        const int* __restrict__ rowptr, const int* __restrict__ deg,
                        const int* __restrict__ srcs,
                        unsigned short* __restrict__ Opre, int n){
  int gid = (blockIdx.x*blockDim.x + threadIdx.x) >> 5;
  int lane = threadIdx.x & 31;
  if (gid >= n) return;
  float4 q = *(const float4*)&qkf[(size_t)gid*H + lane*4];
  float qb = qbf[gid];
  int rp = rowptr[gid], dg = deg[gid];
  const float RS = 0.08838834764831845f;
  float d = 0.f;
  float4 acc = make_float4(0.f,0.f,0.f,0.f);
  int i = 0;
  for (; i+2 <= dg; i += 2){
    int spA = srcs[rp+i], spB = srcs[rp+i+1];
    ushort4 hA = *(const ushort4*)(P1b + (size_t)spA*H + lane*4);
    ushort4 hB = *(const ushort4*)(P1b + (size_t)spB*H + lane*4);
    float4 pA = cvt4(hA), pB = cvt4(hB);
    float psA = dot4(q, pA);
    float psB = dot4(q, pB);
    #pragma unroll
    for (int off=1; off<32; off<<=1){ psA += __shfl_xor(psA,off); psB += __shfl_xor(psB,off); }
    float eA = __expf((psA + qb)*RS), eB = __expf((psB + qb)*RS);
    d += eA + eB;
    acc.x += eA*pA.x + eB*pB.x;
    acc.y += eA*pA.y + eB*pB.y;
    acc.z += eA*pA.z + eB*pB.z;
    acc.w += eA*pA.w + eB*pB.w;
  }
  if (i < dg){
    int sp = srcs[rp+i];
    ushort4 h = *(const ushort4*)(P1b + (size_t)sp*H + lane*4);
    float4 p = cvt4(h);
    float ps = dot4(q, p);
    #pragma unroll
    for (int off=1; off<32; off<<=1) ps += __shfl_xor(ps,off);
    float e = __expf((ps + qb)*RS);
    d += e;
    acc.x += e*p.x; acc.y += e*p.y; acc.z += e*p.z; acc.w += e*p.w;
  }
  float inv = 1.f/(d + 1e-16f);
  ushort4 h;
  h.x = f2b(acc.x*inv); h.y = f2b(acc.y*inv);
  h.z = f2b(acc.z*inv); h.w = f2b(acc.w*inv);
  *(ushort4*)(Opre + (size_t)gid*H + lane*4) = h;
}

extern "C" void kernel_launch(void* const* d_in, const int* in_sizes, int n_in,
                              void* d_out, int out_size, void* d_ws, size_t ws_size,
                              hipStream_t stream){
  const float* x_token  = (const float*)d_in[0];
  const float* x_phrase = (const float*)d_in[1];
  const float* W_emb    = (const float*)d_in[2];
  const float* b_emb    = (const float*)d_in[3];
  const float* Wq_tp = (const float*)d_in[4];  const float* bq_tp = (const float*)d_in[5];
  const float* Wk_tp = (const float*)d_in[6];  const float* bk_tp = (const float*)d_in[7];
  const float* Wv_tp = (const float*)d_in[8];  const float* bv_tp = (const float*)d_in[9];
  const float* Ws_tp = (const float*)d_in[10]; const float* bs_tp = (const float*)d_in[11];
  const float* Wb_tp = (const float*)d_in[12];
  const float* Wq_pt = (const float*)d_in[13]; const float* bq_pt = (const float*)d_in[14];
  const float* Wk_pt = (const float*)d_in[15]; const float* bk_pt = (const float*)d_in[16];
  const float* Wv_pt = (const float*)d_in[17]; const float* bv_pt = (const float*)d_in[18];
  const float* Ws_pt = (const float*)d_in[19]; const float* bs_pt = (const float*)d_in[20];
  const float* Wb_pt = (const float*)d_in[21];
  const float* W_head = (const float*)d_in[22]; const float* b_head = (const float*)d_in[23];
  const int* src_tp = (const int*)d_in[24];
  const int* dst_tp = (const int*)d_in[25];
  const int* src_pt = (const int*)d_in[26];
  const int* dst_pt = (const int*)d_in[27];
  float* out = (float*)d_out;

  // ---- workspace carve ----
  char* base = (char*)d_ws;
  size_t off = 0;
  auto AB = [&](size_t bytes)->void*{ void* p=(void*)(base+off); off += (bytes+15)&~(size_t)15; return p; };
  unsigned short* S1b = (unsigned short*)AB((size_t)NP*H*2);
  unsigned short* P1b = (unsigned short*)AB((size_t)NP*H*2);
  unsigned short* VQ  = (unsigned short*)AB((size_t)NT*H*2);  // Vb early; Opre later
  unsigned short* Sb  = (unsigned short*)AB((size_t)NT*H*2);
  unsigned short* T1b = (unsigned short*)AB((size_t)NT*H*2);  // t1, then t2
  unsigned short* Vb   = VQ;
  unsigned short* Opre = VQ;
  float* qkf = (float*)AB((size_t)NT*H*4);
  float* qbf = (float*)AB((size_t)NT*4);
  float* Wqk = (float*)AB((size_t)H*H*4);
  float* bqk = (float*)AB((size_t)H*4);
  float* vqb = (float*)AB((size_t)H*4);
  float* c0  = (float*)AB(16);
  float* vecs = (float*)AB(8*H*4);
  float* uk1=vecs, *wk1=vecs+H, *uv1=vecs+2*H, *wv1=vecs+3*H;
  float* uq2=vecs+4*H, *wq2=vecs+5*H, *us2=vecs+6*H, *ws2=vecs+7*H;
  float2* ac1  = (float2*)AB((size_t)NP*8);
  float2* ac2  = (float2*)AB((size_t)NP*8);
  float2* dsv2 = (float2*)AB((size_t)NP*8);
  int2* sortedP = (int2*)AB((size_t)NB*BCAP*8);
  int2* sortedT = (int2*)AB((size_t)NB*BCAP*8);
  int*  srcsT   = (int*)AB((size_t)NB*BCAP*4);
  int* rowT = (int*)AB((size_t)NT*4);
  int* degT = (int*)AB((size_t)NT*4);
  int* bcnt = (int*)AB((size_t)2*NB*4);
  int* bcntP = bcnt, * bcntT = bcnt + NB;
  (void)ws_size; (void)in_sizes; (void)n_in; (void)out_size;

  const int gP = CDIV(NP,128), gT = CDIV(NT,128);
  const int nbA = CDIV(NE,2048);

  kvec4<<<4,H,0,stream>>>(W_emb, b_emb,
      Wk_tp, bk_tp, uk1, wk1,
      Wv_tp, bv_tp, uv1, wv1,
      Wq_pt, bq_pt, uq2, wq2,
      Ws_pt, bs_pt, us2, ws2);
  ksetup<<<H,H,0,stream>>>(Wq_pt, Wk_pt, bq_pt, Wqk, bqk);
  kvqb<<<1,H,0,stream>>>(Wq_pt, bq_pt, bk_pt, vqb, c0);

  // bucket-bin both edge lists
  (void)hipMemsetAsync(bcnt, 0, (size_t)2*NB*4, stream);
  passA<1><<<nbA,256,0,stream>>>(dst_tp, src_tp, x_token, 8, bcntP, sortedP, NE);
  passA<0><<<nbA,256,0,stream>>>(dst_pt, src_pt, nullptr, 9, bcntT, sortedT, NE);
  passB_tok<<<NB,512,0,stream>>>(bcntT, sortedT, rowT, degT, srcsT, NT);

  // fused phrase-side GEMMs
  mgemm_ph<<<gP,256,0,stream>>>(x_phrase, NP,
      Wq_tp, bq_tp, uk1, wk1, ac1,
      Ws_tp, bs_tp, S1b,
      Wk_pt, bk_pt, uq2, wq2, ac2,
      Wv_pt, bv_pt, Vb);

  // tconv1
  passB_ph<<<NB,512,0,stream>>>(bcntP, sortedP, ac1, dsv2, NP);
  kcomb1<<<CDIV(NP*32,256),256,0,stream>>>(dsv2, uv1, wv1, S1b, Wb_tp, P1b, NP);

  // tconv2 -> t1
  knode2<<<CDIV(NT*32,256),256,0,stream>>>(x_token, ac2, Vb, rowT, degT, srcsT,
                                           us2, ws2, Wb_pt, T1b, NT);

  // tconv3: qk/qb/s3 from t1; p1-gather node pass; Wv + beta-combine (deg-gated bias)
  mgemm_t3<<<gT,256,0,stream>>>(T1b, NT, Wqk, bqk, qkf, vqb, c0, qbf,
                                Ws_pt, bs_pt, Sb);
  knode3n<<<CDIV(NT*32,256),256,0,stream>>>(qkf, qbf, P1b, rowT, degT, srcsT,
                                            Opre, NT);
  mgemm_cmb<<<gT,256,0,stream>>>(Opre, NT, Wv_pt, bv_pt, Sb, Wb_pt, degT, T1b);

  // head
  mgemm_head<<<gT,256,0,stream>>>(T1b, NT, W_head, b_head, out);
}

// Round 10
// 337.875 us; speedup vs baseline: 1.0349x; 1.0349x over previous
//
#include <hip/hip_runtime.h>
#include <math.h>

#define NT 100000
#define NP 50000
#define NE 800000
#define H 128
#define NB 196
#define BCAP 8192

#define CDIV(a,b) (((a)+(b)-1)/(b))

typedef __attribute__((ext_vector_type(8))) short s16x8;
typedef __attribute__((ext_vector_type(4))) short s16x4;
typedef __attribute__((ext_vector_type(4))) unsigned short u16x4;
typedef __attribute__((ext_vector_type(4))) float f32x4;

static __device__ __forceinline__ float dot4(float4 a, float4 b){
  return a.x*b.x + a.y*b.y + a.z*b.z + a.w*b.w;
}
static __device__ __forceinline__ float b2f(unsigned short u){
  union { unsigned int i; float f; } c; c.i = ((unsigned int)u) << 16; return c.f;
}
static __device__ __forceinline__ unsigned short f2b(float f){
  union { float f; unsigned int i; } c; c.f = f;
  unsigned int x = c.i;
  unsigned int r = (x + 0x7fffu + ((x >> 16) & 1u)) >> 16;   // RNE
  return (unsigned short)r;
}
static __device__ __forceinline__ float4 cvt4(ushort4 h){
  return make_float4(b2f(h.x), b2f(h.y), b2f(h.z), b2f(h.w));
}
static __device__ __forceinline__ float4 cvt4u(u16x4 h){
  return make_float4(b2f(h[0]), b2f(h[1]), b2f(h[2]), b2f(h[3]));
}

// ---------- rank-1 helper vectors ----------
__global__ void kvec4(const float* __restrict__ e, const float* __restrict__ be,
    const float* W0, const float* bi0, float* u0, float* w0,
    const float* W1, const float* bi1, float* u1, float* w1,
    const float* W2, const float* bi2, float* u2, float* w2,
    const float* W3, const float* bi3, float* u3, float* w3){
  const float *W, *bi; float *u, *w;
  switch (blockIdx.x){
    case 0: W=W0; bi=bi0; u=u0; w=w0; break;
    case 1: W=W1; bi=bi1; u=u1; w=w1; break;
    case 2: W=W2; bi=bi2; u=u2; w=w2; break;
    default:W=W3; bi=bi3; u=u3; w=w3; break;
  }
  int j = threadIdx.x;
  float su = 0.f, sw = 0.f;
  for (int i = 0; i < H; ++i) {
    float wv = W[i*H + j];
    su += e[i]*wv;
    sw += be[i]*wv;
  }
  u[j] = su;
  w[j] = sw + bi[j];
}

// ---------- setup: Wqk = Wq @ Wk^T, bqk = bq @ Wk^T ----------
__global__ void ksetup(const float* __restrict__ Wq, const float* __restrict__ Wk,
                       const float* __restrict__ bq, float* __restrict__ Wqk,
                       float* __restrict__ bqk){
  int i = blockIdx.x;
  int m = threadIdx.x;
  __shared__ float wqr[H];
  wqr[m] = Wq[i*H + m];
  __syncthreads();
  const float* wkr = Wk + m*H;
  float s = 0.f;
  for (int j = 0; j < H; ++j) s += wqr[j] * wkr[j];
  Wqk[i*H + m] = s;
  if (i == 0){
    float t = 0.f;
    for (int j = 0; j < H; ++j) t += bq[j] * wkr[j];
    bqk[m] = t;
  }
}
// vqb = Wq @ bk, c0 = bq . bk
__global__ void kvqb(const float* __restrict__ Wq, const float* __restrict__ bq,
                     const float* __restrict__ bk, float* __restrict__ vqb,
                     float* __restrict__ c0){
  int i = threadIdx.x;
  float s = 0.f;
  for (int j = 0; j < H; ++j) s += Wq[i*H + j]*bk[j];
  vqb[i] = s;
  if (i == 0){
    float t = 0.f;
    for (int j = 0; j < H; ++j) t += bq[j]*bk[j];
    *c0 = t;
  }
}

// ---------- kprep: pre-convert W (fp32) -> swizzled bf16 hi|lo LDS image ----------
__global__ void kprep(const float* W0, unsigned short* P0,
                      const float* W1, unsigned short* P1,
                      const float* W2, unsigned short* P2,
                      const float* W3, unsigned short* P3,
                      const float* W4, unsigned short* P4,
                      const float* W5, unsigned short* P5,
                      const float* W6, unsigned short* P6){
  const float* W; unsigned short* P;
  switch (blockIdx.x){
    case 0: W=W0; P=P0; break;
    case 1: W=W1; P=P1; break;
    case 2: W=W2; P=P2; break;
    case 3: W=W3; P=P3; break;
    case 4: W=W4; P=P4; break;
    case 5: W=W5; P=P5; break;
    default:W=W6; P=P6; break;
  }
  int tid = threadIdx.x;
  for (int it = 0; it < 16; ++it){
    int gid = it*256 + tid;
    int n  = gid & 127;
    int kg = gid >> 7;
    int k0 = kg*4;
    float w0 = W[(k0+0)*H + n];
    float w1 = W[(k0+1)*H + n];
    float w2 = W[(k0+2)*H + n];
    float w3 = W[(k0+3)*H + n];
    unsigned short h0=f2b(w0), h1=f2b(w1), h2=f2b(w2), h3=f2b(w3);
    s16x4 hv; hv[0]=(short)h0; hv[1]=(short)h1; hv[2]=(short)h2; hv[3]=(short)h3;
    s16x4 lv; lv[0]=(short)f2b(w0-b2f(h0)); lv[1]=(short)f2b(w1-b2f(h1));
              lv[2]=(short)f2b(w2-b2f(h2)); lv[3]=(short)f2b(w3-b2f(h3));
    int base = n*128 + (((kg>>1) ^ (n&15))<<3) + ((kg&1)<<2);
    *(s16x4*)(P + base) = hv;
    *(s16x4*)(P + 16384 + base) = lv;
  }
}

// ---------- stage: pure 64KB copy of prestaged image into LDS ----------
static __device__ __forceinline__ void stage_pre(const unsigned short* __restrict__ Wpre,
    unsigned short* __restrict__ WHL, int tid){
  const s16x8* src = (const s16x8*)Wpre;
  #pragma unroll
  for (int c = 0; c < 2; ++c){
    s16x8 tmp[8];
    #pragma unroll
    for (int it = 0; it < 8; ++it) tmp[it] = src[(c*8+it)*256 + tid];
    #pragma unroll
    for (int it = 0; it < 8; ++it) *(s16x8*)(WHL + ((c*8+it)*256 + tid)*8) = tmp[it];
  }
}

template<bool USE_AL>
static __device__ __forceinline__ void mfma_pass(const s16x8 AH[2][4], const s16x8 AL[2][4],
    const unsigned short* __restrict__ WH, const unsigned short* __restrict__ WL,
    int l15, int l4, f32x4 acc[2][8]){
  #pragma unroll
  for (int g = 0; g < 2; ++g)
    #pragma unroll
    for (int t = 0; t < 8; ++t){ acc[g][t][0]=0.f; acc[g][t][1]=0.f; acc[g][t][2]=0.f; acc[g][t][3]=0.f; }
  #pragma unroll
  for (int s = 0; s < 4; ++s){
    #pragma unroll
    for (int t = 0; t < 8; ++t){
      int n = t*16 + l15;
      int off = n*128 + (((s*4 + l4) ^ l15)<<3);
      s16x8 BH = *(const s16x8*)(WH + off);
      s16x8 BL = *(const s16x8*)(WL + off);
      #pragma unroll
      for (int g = 0; g < 2; ++g){
        acc[g][t] = __builtin_amdgcn_mfma_f32_16x16x32_bf16(AH[g][s], BH, acc[g][t], 0,0,0);
        acc[g][t] = __builtin_amdgcn_mfma_f32_16x16x32_bf16(AH[g][s], BL, acc[g][t], 0,0,0);
        if constexpr (USE_AL)
          acc[g][t] = __builtin_amdgcn_mfma_f32_16x16x32_bf16(AL[g][s], BH, acc[g][t], 0,0,0);
      }
    }
  }
}

#define EPI_WRITE(ACC, BIAS)                                                    \
  {                                                                             \
    float bb[8];                                                                \
    _Pragma("unroll")                                                           \
    for (int t = 0; t < 8; ++t) bb[t] = BIAS[t*16 + l15];                       \
    _Pragma("unroll")                                                           \
    for (int g = 0; g < 2; ++g){                                                \
      _Pragma("unroll")                                                         \
      for (int t = 0; t < 8; ++t){                                              \
        _Pragma("unroll")                                                       \
        for (int r = 0; r < 4; ++r)                                             \
          EPI[w*32 + g*16 + l4*4 + r][t*16 + l15] = ACC[g][t][r] + bb[t];       \
      }                                                                         \
    }                                                                           \
  }

template<int BF>
static __device__ __forceinline__ void epi_store(void* Y, int ld, int of, int row0, int M,
                                                 int tid, const float (*EPI)[132]){
  #pragma unroll
  for (int it = 0; it < 16; ++it){
    int fid = it*256 + tid;
    int r = fid >> 5, c4 = (fid & 31) << 2;
    int grow = row0 + r;
    if (grow < M){
      float4 v = *(const float4*)&EPI[r][c4];
      if constexpr (BF){
        ushort4 hv; hv.x=f2b(v.x); hv.y=f2b(v.y); hv.z=f2b(v.z); hv.w=f2b(v.w);
        *(ushort4*)((unsigned short*)Y + (size_t)grow*ld + of + c4) = hv;
      } else {
        *(float4*)((float*)Y + (size_t)grow*ld + of + c4) = v;
      }
    }
  }
}

static __device__ __forceinline__ void dots_epi(const f32x4 (&acc)[2][8],
    const float* __restrict__ bias, const float* __restrict__ uvec,
    const float* __restrict__ wvec, float2* __restrict__ acout,
    int row0, int M, int w, int l15, int l4){
  float ub[8], wb[8], bb[8];
  #pragma unroll
  for (int t=0;t<8;++t){ ub[t]=uvec[t*16+l15]; wb[t]=wvec[t*16+l15]; bb[t]=bias[t*16+l15]; }
  #pragma unroll
  for (int g=0; g<2; ++g){
    #pragma unroll
    for (int r=0;r<4;++r){
      float pa=0.f, pc=0.f;
      #pragma unroll
      for (int t=0;t<8;++t){ float y=acc[g][t][r]+bb[t]; pa+=y*ub[t]; pc+=y*wb[t]; }
      #pragma unroll
      for (int o=1;o<16;o<<=1){ pa+=__shfl_xor(pa,o); pc+=__shfl_xor(pc,o); }
      int row=row0+w*32+g*16+l4*4+r;
      if (l15==0 && row<M) acout[row]=make_float2(pa,pc);
    }
  }
}

static __device__ __forceinline__ void load_a_f32(const float* __restrict__ X, int M,
    int row0, int w, int l15, int l4, s16x8 AH[2][4], s16x8 AL[2][4]){
  #pragma unroll
  for (int g = 0; g < 2; ++g){
    int row = row0 + w*32 + g*16 + l15;
    const float* xr = X + (size_t)row*H;
    bool ok = row < M;
    #pragma unroll
    for (int s = 0; s < 4; ++s){
      int kb = s*32 + l4*8;
      float4 f0 = ok ? *(const float4*)(xr+kb)   : make_float4(0.f,0.f,0.f,0.f);
      float4 f1 = ok ? *(const float4*)(xr+kb+4) : make_float4(0.f,0.f,0.f,0.f);
      float xs[8] = {f0.x,f0.y,f0.z,f0.w,f1.x,f1.y,f1.z,f1.w};
      s16x8 h, lo;
      #pragma unroll
      for (int e = 0; e < 8; ++e){
        unsigned short hh = f2b(xs[e]);
        h[e]  = (short)hh;
        lo[e] = (short)f2b(xs[e] - b2f(hh));
      }
      AH[g][s] = h; AL[g][s] = lo;
    }
  }
}
static __device__ __forceinline__ void load_a_bf16(const unsigned short* __restrict__ Xb, int M,
    int row0, int w, int l15, int l4, s16x8 AH[2][4]){
  #pragma unroll
  for (int g = 0; g < 2; ++g){
    int row = row0 + w*32 + g*16 + l15;
    const unsigned short* xr = Xb + (size_t)row*H;
    bool ok = row < M;
    #pragma unroll
    for (int s = 0; s < 4; ++s){
      s16x8 h = {0,0,0,0,0,0,0,0};
      if (ok) h = *(const s16x8*)(xr + s*32 + l4*8);
      AH[g][s] = h;
    }
  }
}

// ---------- fused phrase-side GEMM: 4 passes sharing X fragments ----------
__launch_bounds__(256)
__global__ void mgemm_ph(const float* __restrict__ X, int M,
    const unsigned short* __restrict__ WqP, const float* __restrict__ bq,
    const float* __restrict__ uk, const float* __restrict__ wk, float2* __restrict__ ac1,
    const unsigned short* __restrict__ WsP, const float* __restrict__ bs, unsigned short* __restrict__ S1b,
    const unsigned short* __restrict__ WkP, const float* __restrict__ bk,
    const float* __restrict__ uq, const float* __restrict__ wq, float2* __restrict__ ac2,
    const unsigned short* __restrict__ WvP, const float* __restrict__ bv, unsigned short* __restrict__ Vb){
  __shared__ __align__(16) char smem[128*132*4];
  unsigned short* WHL = (unsigned short*)smem;
  float (*EPI)[132] = (float(*)[132])smem;
  int tid=threadIdx.x, lane=tid&63, w=tid>>6, l15=lane&15, l4=lane>>4;
  int row0 = blockIdx.x*128;

  s16x8 AH[2][4], AL[2][4];
  load_a_f32(X, M, row0, w, l15, l4, AH, AL);

  f32x4 acc[2][8];
  stage_pre(WqP, WHL, tid); __syncthreads();
  mfma_pass<true>(AH, AL, WHL, WHL+16384, l15, l4, acc);
  dots_epi(acc, bq, uk, wk, ac1, row0, M, w, l15, l4);
  __syncthreads();
  stage_pre(WsP, WHL, tid); __syncthreads();
  mfma_pass<true>(AH, AL, WHL, WHL+16384, l15, l4, acc);
  __syncthreads(); EPI_WRITE(acc, bs); __syncthreads();
  epi_store<1>(S1b, H, 0, row0, M, tid, EPI);
  __syncthreads();
  stage_pre(WkP, WHL, tid); __syncthreads();
  mfma_pass<true>(AH, AL, WHL, WHL+16384, l15, l4, acc);
  dots_epi(acc, bk, uq, wq, ac2, row0, M, w, l15, l4);
  __syncthreads();
  stage_pre(WvP, WHL, tid); __syncthreads();
  mfma_pass<true>(AH, AL, WHL, WHL+16384, l15, l4, acc);
  __syncthreads(); EPI_WRITE(acc, bv); __syncthreads();
  epi_store<1>(Vb, H, 0, row0, M, tid, EPI);
}

// ---------- tconv3 front GEMM: qk = t1@Wqk + bqk (fp32), qb dots, s3 -> Sb ----------
__launch_bounds__(256)
__global__ void mgemm_t3(const unsigned short* __restrict__ T1b, int M,
    const unsigned short* __restrict__ WqkP, const float* __restrict__ bqk,
    float* __restrict__ qkf,
    const float* __restrict__ vqb, const float* __restrict__ c0,
    float* __restrict__ qbf,
    const unsigned short* __restrict__ WsP, const float* __restrict__ bs,
    unsigned short* __restrict__ Sb){
  __shared__ __align__(16) char smem[128*132*4];
  unsigned short* WHL = (unsigned short*)smem;
  float (*EPI)[132] = (float(*)[132])smem;
  int tid=threadIdx.x, lane=tid&63, w=tid>>6, l15=lane&15, l4=lane>>4;
  int row0 = blockIdx.x*128;

  s16x8 AH[2][4];
  load_a_bf16(T1b, M, row0, w, l15, l4, AH);

  float cc0 = *c0;
  #pragma unroll
  for (int g = 0; g < 2; ++g){
    float p = 0.f;
    #pragma unroll
    for (int s = 0; s < 4; ++s){
      #pragma unroll
      for (int e = 0; e < 8; ++e)
        p += b2f((unsigned short)AH[g][s][e]) * vqb[s*32 + l4*8 + e];
    }
    p += __shfl_xor(p, 16);
    p += __shfl_xor(p, 32);
    int row = row0 + w*32 + g*16 + l15;
    if (l4 == 0 && row < M) qbf[row] = p + cc0;
  }

  stage_pre(WqkP, WHL, tid); __syncthreads();
  f32x4 acc[2][8];
  mfma_pass<false>(AH, nullptr, WHL, WHL+16384, l15, l4, acc);
  __syncthreads();
  EPI_WRITE(acc, bqk);
  __syncthreads();
  epi_store<0>(qkf, H, 0, row0, M, tid, EPI);
  __syncthreads();

  stage_pre(WsP, WHL, tid); __syncthreads();
  f32x4 acc2[2][8];
  mfma_pass<false>(AH, nullptr, WHL, WHL+16384, l15, l4, acc2);
  __syncthreads();
  EPI_WRITE(acc2, bs);
  __syncthreads();
  epi_store<1>(Sb, H, 0, row0, M, tid, EPI);
}

// ---------- fused tconv3-back + head: t2 in LDS, out = t2@W_head + b_head ----------
__launch_bounds__(256)
__global__ void mgemm_cmbh(const unsigned short* __restrict__ Opre, int M,
    const unsigned short* __restrict__ WvP, const float* __restrict__ bv,
    const unsigned short* __restrict__ Sb, const float* __restrict__ Wb,
    const int* __restrict__ deg,
    const unsigned short* __restrict__ WhP, const float* __restrict__ bh,
    float* __restrict__ out){
  __shared__ __align__(16) unsigned short WHL[32768];       // 64KB
  __shared__ __align__(16) unsigned short SLDS[128][132];   // 33.8KB (padded: conflict-free)
  int tid=threadIdx.x, lane=tid&63, w=tid>>6, l15=lane&15, l4=lane>>4;
  int row0 = blockIdx.x*128;

  s16x8 AH[2][4];
  load_a_bf16(Opre, M, row0, w, l15, l4, AH);

  stage_pre(WvP, WHL, tid);
  // stage Sb tile into padded SLDS
  #pragma unroll
  for (int it = 0; it < 8; ++it){
    int id = it*256 + tid;
    int r = id >> 4, c8 = (id & 15) << 3;
    int grow = row0 + r;
    s16x8 sv = {0,0,0,0,0,0,0,0};
    if (grow < M) sv = *(const s16x8*)(Sb + (size_t)grow*H + c8);
    *(s16x8*)&SLDS[r][c8] = sv;
  }
  __syncthreads();

  f32x4 acc[2][8];
  mfma_pass<false>(AH, nullptr, WHL, WHL+16384, l15, l4, acc);

  // epilogue pass 1: beta-combine (deg-gated bias), write t2 bf16 IN PLACE into SLDS
  {
    float bvv[8], wbA[8], wbB[8], wbC[8];
    #pragma unroll
    for (int t = 0; t < 8; ++t){
      int col = t*16 + l15;
      bvv[t] = bv[col];
      wbA[t] = Wb[col]; wbB[t] = Wb[H + col]; wbC[t] = Wb[2*H + col];
    }
    #pragma unroll
    for (int g = 0; g < 2; ++g){
      #pragma unroll
      for (int r = 0; r < 4; ++r){
        int rl = w*32 + g*16 + l4*4 + r;
        int row = row0 + rl;
        float bsc = (row < M && deg[row] > 0) ? 1.f : 0.f;
        float o[8], sk[8];
        float part = 0.f;
        #pragma unroll
        for (int t = 0; t < 8; ++t){
          o[t] = acc[g][t][r] + bvv[t]*bsc;
          sk[t] = b2f(SLDS[rl][t*16 + l15]);
          part += o[t]*wbA[t] + sk[t]*wbB[t] + (o[t]-sk[t])*wbC[t];
        }
        #pragma unroll
        for (int of = 1; of < 16; of <<= 1) part += __shfl_xor(part, of);
        float beta = 1.f/(1.f + __expf(-part));
        #pragma unroll
        for (int t = 0; t < 8; ++t){
          float vv = beta*sk[t] + (1.f-beta)*o[t];
          SLDS[rl][t*16 + l15] = f2b(vv);     // same addresses this thread read
        }
      }
    }
  }
  __syncthreads();   // t2 complete; all waves done with WHL pass 1

  // head pass: A = t2 from SLDS, W_head into WHL
  s16x8 A2[2][4];
  #pragma unroll
  for (int g = 0; g < 2; ++g){
    int rl = w*32 + g*16 + l15;
    #pragma unroll
    for (int s = 0; s < 4; ++s)
      A2[g][s] = *(const s16x8*)&SLDS[rl][s*32 + l4*8];
  }
  stage_pre(WhP, WHL, tid);
  __syncthreads();

  f32x4 a2[2][8];
  mfma_pass<false>(A2, nullptr, WHL, WHL+16384, l15, l4, a2);

  float bhh[8];
  #pragma unroll
  for (int t = 0; t < 8; ++t) bhh[t] = bh[t*16 + l15];
  #pragma unroll
  for (int g = 0; g < 2; ++g){
    #pragma unroll
    for (int r = 0; r < 4; ++r){
      int row = row0 + w*32 + g*16 + l4*4 + r;
      if (row < M){
        float* orow = out + (size_t)row*H;
        #pragma unroll
        for (int t = 0; t < 8; ++t)
          orow[t*16 + l15] = a2[g][t][r] + bhh[t];
      }
    }
  }
}

// ---------- passA: bucket-bin edges ----------
template<int GATHER>
__launch_bounds__(256)
__global__ void passA(const int* __restrict__ dst, const int* __restrict__ src,
                      const float* __restrict__ xv, int shift,
                      int* __restrict__ bcnt, int2* __restrict__ out, int n){
  __shared__ int hist[NB];
  __shared__ int base[NB];
  __shared__ int cur[NB];
  int tid = threadIdx.x;
  for (int i = tid; i < NB; i += 256){ hist[i]=0; cur[i]=0; }
  __syncthreads();
  int e0 = blockIdx.x*2048;
  int d[8], s[8];
  #pragma unroll
  for (int k = 0; k < 8; ++k){
    int i = e0 + k*256 + tid;
    if (i < n){ d[k] = dst[i]; s[k] = src[i]; }
    else d[k] = -1;
  }
  #pragma unroll
  for (int k = 0; k < 8; ++k)
    if (d[k] >= 0) atomicAdd(&hist[d[k]>>shift], 1);
  __syncthreads();
  for (int b = tid; b < NB; b += 256)
    base[b] = hist[b] ? atomicAdd(&bcnt[b], hist[b]) : 0;
  __syncthreads();
  #pragma unroll
  for (int k = 0; k < 8; ++k){
    if (d[k] >= 0){
      int b = d[k] >> shift;
      int loc = atomicAdd(&cur[b], 1);
      int2 rec;
      if constexpr (GATHER) rec.x = __float_as_int(xv[s[k]]);
      else                  rec.x = s[k];
      rec.y = d[k] - (b << shift);
      out[(size_t)b*BCAP + base[b] + loc] = rec;
    }
  }
}

// ---------- passB phrase ----------
__launch_bounds__(512)
__global__ void passB_ph(const int* __restrict__ bcnt, const int2* __restrict__ sorted,
                         const float2* __restrict__ ac, float2* __restrict__ dsv, int np){
  __shared__ float2 acl[256];
  __shared__ float accx[256];
  __shared__ float accy[256];
  int b = blockIdx.x, tid = threadIdx.x;
  int p0 = b*256;
  if (tid < 256){
    int p = p0 + tid;
    acl[tid] = (p < np) ? ac[p] : make_float2(0.f,0.f);
    accx[tid] = 0.f; accy[tid] = 0.f;
  }
  __syncthreads();
  int n = bcnt[b];
  const int2* e = sorted + (size_t)b*BCAP;
  const float RS = 0.08838834764831845f;
  for (int i = tid; i < n; i += 512){
    int2 ed = e[i];
    float x = __int_as_float(ed.x);
    float2 a = acl[ed.y];
    float ex = __expf((x*a.x + a.y)*RS);
    atomicAdd(&accx[ed.y], ex);
    atomicAdd(&accy[ed.y], ex*x);
  }
  __syncthreads();
  if (tid < 256){
    int p = p0 + tid;
    if (p < np) dsv[p] = make_float2(accx[tid], accy[tid]);
  }
}

// ---------- passB token: per-bucket CSR ----------
__launch_bounds__(512)
__global__ void passB_tok(const int* __restrict__ bcnt, const int2* __restrict__ sorted,
                          int* __restrict__ rowptr, int* __restrict__ deg,
                          int* __restrict__ srcs, int ntok){
  __shared__ int cnt[512];
  __shared__ int scn[512];
  __shared__ int cur[512];
  int b = blockIdx.x, tid = threadIdx.x;
  cnt[tid] = 0; cur[tid] = 0;
  __syncthreads();
  int n = bcnt[b];
  const int2* e = sorted + (size_t)b*BCAP;
  for (int i = tid; i < n; i += 512) atomicAdd(&cnt[e[i].y], 1);
  __syncthreads();
  int myc = cnt[tid];
  scn[tid] = myc;
  __syncthreads();
  for (int off = 1; off < 512; off <<= 1){
    int u = (tid >= off) ? scn[tid-off] : 0;
    __syncthreads();
    scn[tid] += u;
    __syncthreads();
  }
  int excl = scn[tid] - myc;
  int tok = b*512 + tid;
  if (tok < ntok){ rowptr[tok] = b*BCAP + excl; deg[tok] = myc; }
  __syncthreads();
  cnt[tid] = excl;
  __syncthreads();
  for (int i = tid; i < n; i += 512){
    int2 ed = e[i];
    int pos = cnt[ed.y] + atomicAdd(&cur[ed.y], 1);
    srcs[(size_t)b*BCAP + pos] = ed.x;
  }
}

// ---------- beta gate + combine; OB: bf16 output ----------
template<int OB>
static __device__ __forceinline__ void beta_combine(float4 o, float4 sk,
    const float* __restrict__ Wb, int lane, bool leaky, void* __restrict__ dstRow){
  float4 wb0 = *(const float4*)&Wb[lane*4];
  float4 wb1 = *(const float4*)&Wb[H   + lane*4];
  float4 wb2 = *(const float4*)&Wb[2*H + lane*4];
  float4 dv = make_float4(o.x-sk.x, o.y-sk.y, o.z-sk.z, o.w-sk.w);
  float part = dot4(o,wb0) + dot4(sk,wb1) + dot4(dv,wb2);
  #pragma unroll
  for (int off=1; off<32; off<<=1) part += __shfl_xor(part, off);
  float beta = 1.f/(1.f + __expf(-part));
  float4 r;
  r.x = beta*sk.x + (1.f-beta)*o.x;
  r.y = beta*sk.y + (1.f-beta)*o.y;
  r.z = beta*sk.z + (1.f-beta)*o.z;
  r.w = beta*sk.w + (1.f-beta)*o.w;
  if (leaky){
    r.x = r.x>0.f? r.x : 0.01f*r.x;
    r.y = r.y>0.f? r.y : 0.01f*r.y;
    r.z = r.z>0.f? r.z : 0.01f*r.z;
    r.w = r.w>0.f? r.w : 0.01f*r.w;
  }
  if constexpr (OB){
    ushort4 h; h.x=f2b(r.x); h.y=f2b(r.y); h.z=f2b(r.z); h.w=f2b(r.w);
    *(ushort4*)((unsigned short*)dstRow + lane*4) = h;
  } else {
    *(float4*)((float*)dstRow + lane*4) = r;
  }
}

__global__ void kcomb1(const float2* __restrict__ dsv,
                       const float* __restrict__ uv, const float* __restrict__ wv,
                       const unsigned short* __restrict__ S, const float* __restrict__ Wb,
                       unsigned short* __restrict__ out, int n){
  int gid = (blockIdx.x*blockDim.x + threadIdx.x) >> 5;
  int lane = threadIdx.x & 31;
  if (gid >= n) return;
  float2 ds = dsv[gid];
  float d = ds.x, sv = ds.y;
  float inv = 1.f/(d + 1e-16f);
  float4 u4 = *(const float4*)&uv[lane*4];
  float4 w4 = *(const float4*)&wv[lane*4];
  float4 o = make_float4((sv*u4.x + d*w4.x)*inv, (sv*u4.y + d*w4.y)*inv,
                         (sv*u4.z + d*w4.z)*inv, (sv*u4.w + d*w4.w)*inv);
  u16x4 sh4 = __builtin_nontemporal_load((const u16x4*)(S + (size_t)gid*H + lane*4));
  float4 sk = cvt4u(sh4);
  beta_combine<1>(o, sk, Wb, lane, true, out + (size_t)gid*H);
}

// ---------- tconv2: no-max, 2-way unrolled bf16 V gather ----------
__global__ void knode2(const float* __restrict__ x_tok, const float2* __restrict__ ac,
                       const unsigned short* __restrict__ Vb,
                       const int* __restrict__ rowptr, const int* __restrict__ deg,
                       const int* __restrict__ srcs,
                       const float* __restrict__ us, const float* __restrict__ ws,
                       const float* __restrict__ Wb, unsigned short* __restrict__ out, int n){
  int gid = (blockIdx.x*blockDim.x + threadIdx.x) >> 5;
  int lane = threadIdx.x & 31;
  if (gid >= n) return;
  float xt = x_tok[gid];
  int rp = rowptr[gid], dg = deg[gid];
  const float RS = 0.08838834764831845f;
  float d = 0.f;
  float4 acc = make_float4(0.f,0.f,0.f,0.f);
  int i = 0;
  for (; i+2 <= dg; i += 2){
    int spA = srcs[rp+i], spB = srcs[rp+i+1];
    ushort4 hA = *(const ushort4*)(Vb + (size_t)spA*H + lane*4);
    ushort4 hB = *(const ushort4*)(Vb + (size_t)spB*H + lane*4);
    float2 aA = ac[spA], aB = ac[spB];
    float eA = __expf((xt*aA.x + aA.y)*RS);
    float eB = __expf((xt*aB.x + aB.y)*RS);
    float4 vA = cvt4(hA), vB = cvt4(hB);
    d += eA + eB;
    acc.x += eA*vA.x + eB*vB.x;
    acc.y += eA*vA.y + eB*vB.y;
    acc.z += eA*vA.z + eB*vB.z;
    acc.w += eA*vA.w + eB*vB.w;
  }
  if (i < dg){
    int sp = srcs[rp+i];
    ushort4 hv = *(const ushort4*)(Vb + (size_t)sp*H + lane*4);
    float2 a = ac[sp];
    float e = __expf((xt*a.x + a.y)*RS);
    float4 v = cvt4(hv);
    d += e;
    acc.x += e*v.x; acc.y += e*v.y; acc.z += e*v.z; acc.w += e*v.w;
  }
  float inv = 1.f/(d + 1e-16f);
  float4 o = make_float4(acc.x*inv, acc.y*inv, acc.z*inv, acc.w*inv);
  float4 u4 = *(const float4*)&us[lane*4];
  float4 w4 = *(const float4*)&ws[lane*4];
  float4 sk = make_float4(xt*u4.x+w4.x, xt*u4.y+w4.y, xt*u4.z+w4.z, xt*u4.w+w4.w);
  beta_combine<1>(o, sk, Wb, lane, true, out + (size_t)gid*H);
}

// ---------- tconv3 node: gather p1 only (256B/edge), fp32 qk ----------
__global__ void knode3n(const float* __restrict__ qkf, const float* __restrict__ qbf,
                        const unsigned short* __restrict__ P1b,
                        const int* __restrict__ rowptr, const int* __restrict__ deg,
                        const int* __restrict__ srcs,
                        unsigned short* __restrict__ Opre, int n){
  int gid = (blockIdx.x*blockDim.x + threadIdx.x) >> 5;
  int lane = threadIdx.x & 31;
  if (gid >= n) return;
  float4 q = *(const float4*)&qkf[(size_t)gid*H + lane*4];
  float qb = qbf[gid];
  int rp = rowptr[gid], dg = deg[gid];
  const float RS = 0.08838834764831845f;
  float d = 0.f;
  float4 acc = make_float4(0.f,0.f,0.f,0.f);
  int i = 0;
  for (; i+2 <= dg; i += 2){
    int spA = srcs[rp+i], spB = srcs[rp+i+1];
    ushort4 hA = *(const ushort4*)(P1b + (size_t)spA*H + lane*4);
    ushort4 hB = *(const ushort4*)(P1b + (size_t)spB*H + lane*4);
    float4 pA = cvt4(hA), pB = cvt4(hB);
    float psA = dot4(q, pA);
    float psB = dot4(q, pB);
    #pragma unroll
    for (int off=1; off<32; off<<=1){ psA += __shfl_xor(psA,off); psB += __shfl_xor(psB,off); }
    float eA = __expf((psA + qb)*RS), eB = __expf((psB + qb)*RS);
    d += eA + eB;
    acc.x += eA*pA.x + eB*pB.x;
    acc.y += eA*pA.y + eB*pB.y;
    acc.z += eA*pA.z + eB*pB.z;
    acc.w += eA*pA.w + eB*pB.w;
  }
  if (i < dg){
    int sp = srcs[rp+i];
    ushort4 h = *(const ushort4*)(P1b + (size_t)sp*H + lane*4);
    float4 p = cvt4(h);
    float ps = dot4(q, p);
    #pragma unroll
    for (int off=1; off<32; off<<=1) ps += __shfl_xor(ps,off);
    float e = __expf((ps + qb)*RS);
    d += e;
    acc.x += e*p.x; acc.y += e*p.y; acc.z += e*p.z; acc.w += e*p.w;
  }
  float inv = 1.f/(d + 1e-16f);
  ushort4 h;
  h.x = f2b(acc.x*inv); h.y = f2b(acc.y*inv);
  h.z = f2b(acc.z*inv); h.w = f2b(acc.w*inv);
  *(ushort4*)(Opre + (size_t)gid*H + lane*4) = h;
}

extern "C" void kernel_launch(void* const* d_in, const int* in_sizes, int n_in,
                              void* d_out, int out_size, void* d_ws, size_t ws_size,
                              hipStream_t stream){
  const float* x_token  = (const float*)d_in[0];
  const float* x_phrase = (const float*)d_in[1];
  const float* W_emb    = (const float*)d_in[2];
  const float* b_emb    = (const float*)d_in[3];
  const float* Wq_tp = (const float*)d_in[4];  const float* bq_tp = (const float*)d_in[5];
  const float* Wk_tp = (const float*)d_in[6];  const float* bk_tp = (const float*)d_in[7];
  const float* Wv_tp = (const float*)d_in[8];  const float* bv_tp = (const float*)d_in[9];
  const float* Ws_tp = (const float*)d_in[10]; const float* bs_tp = (const float*)d_in[11];
  const float* Wb_tp = (const float*)d_in[12];
  const float* Wq_pt = (const float*)d_in[13]; const float* bq_pt = (const float*)d_in[14];
  const float* Wk_pt = (const float*)d_in[15]; const float* bk_pt = (const float*)d_in[16];
  const float* Wv_pt = (const float*)d_in[17]; const float* bv_pt = (const float*)d_in[18];
  const float* Ws_pt = (const float*)d_in[19]; const float* bs_pt = (const float*)d_in[20];
  const float* Wb_pt = (const float*)d_in[21];
  const float* W_head = (const float*)d_in[22]; const float* b_head = (const float*)d_in[23];
  const int* src_tp = (const int*)d_in[24];
  const int* dst_tp = (const int*)d_in[25];
  const int* src_pt = (const int*)d_in[26];
  const int* dst_pt = (const int*)d_in[27];
  float* out = (float*)d_out;

  // ---- workspace carve ----
  char* base = (char*)d_ws;
  size_t off = 0;
  auto AB = [&](size_t bytes)->void*{ void* p=(void*)(base+off); off += (bytes+15)&~(size_t)15; return p; };
  unsigned short* S1b = (unsigned short*)AB((size_t)NP*H*2);
  unsigned short* P1b = (unsigned short*)AB((size_t)NP*H*2);
  unsigned short* VQ  = (unsigned short*)AB((size_t)NT*H*2);  // Vb early; Opre later
  unsigned short* Sb  = (unsigned short*)AB((size_t)NT*H*2);
  unsigned short* T1b = (unsigned short*)AB((size_t)NT*H*2);  // t1
  unsigned short* Vb   = VQ;
  unsigned short* Opre = VQ;
  float* qkf = (float*)AB((size_t)NT*H*4);
  float* qbf = (float*)AB((size_t)NT*4);
  float* Wqk = (float*)AB((size_t)H*H*4);
  float* bqk = (float*)AB((size_t)H*4);
  float* vqb = (float*)AB((size_t)H*4);
  float* c0  = (float*)AB(16);
  // prestaged bf16 hi|lo weight images (32768 shorts each)
  unsigned short* PQ1 = (unsigned short*)AB(32768*2);
  unsigned short* PS1 = (unsigned short*)AB(32768*2);
  unsigned short* PK2 = (unsigned short*)AB(32768*2);
  unsigned short* PV2 = (unsigned short*)AB(32768*2);
  unsigned short* PS3 = (unsigned short*)AB(32768*2);
  unsigned short* PHD = (unsigned short*)AB(32768*2);
  unsigned short* PQK = (unsigned short*)AB(32768*2);
  float* vecs = (float*)AB(8*H*4);
  float* uk1=vecs, *wk1=vecs+H, *uv1=vecs+2*H, *wv1=vecs+3*H;
  float* uq2=vecs+4*H, *wq2=vecs+5*H, *us2=vecs+6*H, *ws2=vecs+7*H;
  float2* ac1  = (float2*)AB((size_t)NP*8);
  float2* ac2  = (float2*)AB((size_t)NP*8);
  float2* dsv2 = (float2*)AB((size_t)NP*8);
  int2* sortedP = (int2*)AB((size_t)NB*BCAP*8);
  int2* sortedT = (int2*)AB((size_t)NB*BCAP*8);
  int*  srcsT   = (int*)AB((size_t)NB*BCAP*4);
  int* rowT = (int*)AB((size_t)NT*4);
  int* degT = (int*)AB((size_t)NT*4);
  int* bcnt = (int*)AB((size_t)2*NB*4);
  int* bcntP = bcnt, * bcntT = bcnt + NB;
  (void)ws_size; (void)in_sizes; (void)n_in; (void)out_size;

  const int gP = CDIV(NP,128), gT = CDIV(NT,128);
  const int nbA = CDIV(NE,2048);

  kvec4<<<4,H,0,stream>>>(W_emb, b_emb,
      Wk_tp, bk_tp, uk1, wk1,
      Wv_tp, bv_tp, uv1, wv1,
      Wq_pt, bq_pt, uq2, wq2,
      Ws_pt, bs_pt, us2, ws2);
  ksetup<<<H,H,0,stream>>>(Wq_pt, Wk_pt, bq_pt, Wqk, bqk);
  kvqb<<<1,H,0,stream>>>(Wq_pt, bq_pt, bk_pt, vqb, c0);
  kprep<<<7,256,0,stream>>>(Wq_tp, PQ1, Ws_tp, PS1, Wk_pt, PK2, Wv_pt, PV2,
                            Ws_pt, PS3, W_head, PHD, Wqk, PQK);

  // bucket-bin both edge lists
  (void)hipMemsetAsync(bcnt, 0, (size_t)2*NB*4, stream);
  passA<1><<<nbA,256,0,stream>>>(dst_tp, src_tp, x_token, 8, bcntP, sortedP, NE);
  passA<0><<<nbA,256,0,stream>>>(dst_pt, src_pt, nullptr, 9, bcntT, sortedT, NE);
  passB_tok<<<NB,512,0,stream>>>(bcntT, sortedT, rowT, degT, srcsT, NT);

  // fused phrase-side GEMMs
  mgemm_ph<<<gP,256,0,stream>>>(x_phrase, NP,
      PQ1, bq_tp, uk1, wk1, ac1,
      PS1, bs_tp, S1b,
      PK2, bk_pt, uq2, wq2, ac2,
      PV2, bv_pt, Vb);

  // tconv1
  passB_ph<<<NB,512,0,stream>>>(bcntP, sortedP, ac1, dsv2, NP);
  kcomb1<<<CDIV(NP*32,256),256,0,stream>>>(dsv2, uv1, wv1, S1b, Wb_tp, P1b, NP);

  // tconv2 -> t1
  knode2<<<CDIV(NT*32,256),256,0,stream>>>(x_token, ac2, Vb, rowT, degT, srcsT,
                                           us2, ws2, Wb_pt, T1b, NT);

  // tconv3: qk/qb/s3 from t1; p1-gather node pass; fused Wv+beta+head
  mgemm_t3<<<gT,256,0,stream>>>(T1b, NT, PQK, bqk, qkf, vqb, c0, qbf,
                                PS3, bs_pt, Sb);
  knode3n<<<CDIV(NT*32,256),256,0,stream>>>(qkf, qbf, P1b, rowT, degT, srcsT,
                                            Opre, NT);
  mgemm_cmbh<<<gT,256,0,stream>>>(Opre, NT, PV2, bv_pt, Sb, Wb_pt, degT,
                                  PHD, b_head, out);
}